// Round 9
// baseline (143.819 us; speedup 1.0000x reference)
//
#include <hip/hip_runtime.h>
#include <cstdint>

// Composite-filter formulation:
//   out[o] = sum_{k=0..54} Cp[r][k] * x[n0 - k],
//     r = (2o+32) % 3, n0 = (2o+32-r)/3,
//     Cp[p][k] = C[p+3k], C[j] = sum_m b[m]*h[j-2m]
// fused_fast covers 50 <= o < n_out; boundary kernel covers o<50 and o>=n_out.
//
// R8 post-mortem: register double-buffer spilled (VGPR=96 < 128 needed; VALU
// busy 21us >> 8.8us FMA floor). R9: LDS double-buffer with global_load_lds
// async DMA (zero VGPR staging) + persistent 4-tile blocks. DMA for tile t+1
// issues at phase start; the __syncthreads vmcnt drain lands after tile t's
// 1320-cycle FMA stream -> latency hidden structurally, allocator-proof.

#define TPB 256
#define RPT 12                    // outputs per thread
#define OTILE (TPB * RPT)         // 3072 outputs per tile
#define NTILES 4096               // n_out / OTILE
#define TPBK 4                    // tiles per block
#define NBLOCKS (NTILES / TPBK)   // 1024
#define XT 2112                   // floats per LDS buffer (2104 used)
#define NTAPS 55
#define CPSTRIDE 56               // phase-major coeff stride (zero-padded, float4-aligned)

__global__ void build_coeffs(const float* __restrict__ h,
                             const float* __restrict__ b,
                             float* __restrict__ cp) {
    __shared__ float h_s[63];
    __shared__ float b_s[51];
    const int tid = threadIdx.x;
    if (tid < 63) h_s[tid] = h[tid];
    if (tid < 51) b_s[tid] = b[tid];
    __syncthreads();
    for (int idx = tid; idx < 3 * CPSTRIDE; idx += blockDim.x) {
        const int p = idx / CPSTRIDE;
        const int k = idx - p * CPSTRIDE;
        float acc = 0.0f;
        if (k < NTAPS) {
            const int j = p + 3 * k;
            for (int m = 0; m <= 50; ++m) {
                const int hi = j - 2 * m;
                if (hi >= 0 && hi <= 62) acc += b_s[m] * h_s[hi];
            }
        }
        cp[idx] = acc;
    }
}

// Block 0 = head (o in [0,50)), block 1 = tail (o in [n_out, out_size)).
__global__ __launch_bounds__(128) void boundary_fix(
    const float* __restrict__ x, const float* __restrict__ h,
    const float* __restrict__ b, float* __restrict__ out,
    int n_in, int n_out, int out_size)
{
    __shared__ float h_s[63];
    __shared__ float b_s[51];
    __shared__ float x_s[64];
    __shared__ float u_s[50];

    const int tid = threadIdx.x;
    if (tid < 63) h_s[tid] = h[tid];
    if (tid < 51) b_s[tid] = b[tid];

    if (blockIdx.x == 0) {
        if (tid < 44) x_s[tid] = (tid < n_in) ? x[tid] : 0.0f;
        __syncthreads();
        if (tid < 50) {
            const int s  = 2 * tid + 32;
            const int p0 = s % 3;
            const int q  = s / 3;
            float u = 0.0f;
            #pragma unroll
            for (int i = 0; i <= 20; ++i) {
                const int xi = q - i;
                u += h_s[p0 + 3 * i] * ((xi >= 0) ? x_s[xi] : 0.0f);
            }
            u_s[tid] = u;
        }
        __syncthreads();
        if (tid < 50) {
            float acc = 0.0f;
            for (int t = 0; t <= tid; ++t) acc += b_s[tid - t] * u_s[t];
            out[tid] = acc;
        }
    } else {
        const int t0   = n_out - 50;
        const int qmin = (2 * t0 + 32) / 3;
        const int xb   = qmin - 20;
        if (tid < 64) {
            const int xi = xb + tid;
            x_s[tid] = (xi >= 0 && xi < n_in) ? x[xi] : 0.0f;
        }
        __syncthreads();
        if (tid < 50) {
            const int t  = t0 + tid;
            const int s  = 2 * t + 32;
            const int p0 = s % 3;
            const int q  = s / 3;
            const int base = q - xb;
            float u = 0.0f;
            #pragma unroll
            for (int i = 0; i <= 20; ++i)
                u += h_s[p0 + 3 * i] * x_s[base - i];
            u_s[tid] = u;
        }
        __syncthreads();
        const int n_tail = out_size - n_out;   // 96
        if (tid < n_tail) {
            float acc = 0.0f;
            for (int j = tid; j <= 49; ++j) acc += b_s[tid + 50 - j] * u_s[j];
            out[n_out + tid] = acc;
        }
    }
}

// ---- async global->LDS DMA (CK-style addrspace casts) ----
__device__ __forceinline__ void async_copy16(const float* gp, float* lp) {
    auto g = (const __attribute__((address_space(1))) unsigned int*)(uintptr_t)gp;
    auto l = (__attribute__((address_space(3))) unsigned int*)(uintptr_t)lp;
    __builtin_amdgcn_global_load_lds(g, l, 16, 0, 0);
}

// Main 2048 floats of a tile via DMA (wave-uniform base + lane*16B pattern).
__device__ __forceinline__ void stage_dma(const float* __restrict__ x,
                                          float* dst, int base, int tid) {
    async_copy16(x + base + 4 * tid,        dst + 4 * tid);
    async_copy16(x + base + 1024 + 4 * tid, dst + 1024 + 4 * tid);
}

// Guarded full staging for edge tiles (zero-padded).
__device__ __forceinline__ void stage_edge(const float* __restrict__ x,
                                           float* dst, int base, int n_in, int tid) {
    for (int i = tid; i < XT; i += TPB) {
        const int n = base + i;
        dst[i] = (n >= 0 && n < n_in) ? x[n] : 0.0f;
    }
}

// Group g covers taps k=4g..4g+3 for 12 outputs d=0..11.
// delta_d = {0,1,2,2,3,4,4,5,6,6,7,8}, phase r_d = (2+2d)%3 -> q2/q1/q0 cycle.
#define GRP12(g, A, B, C, D) {                                          \
    const float4 q2 = c2q[g];                                           \
    const float4 q1 = c1q[g];                                           \
    const float4 q0 = c0q[g];                                           \
    a0  += q2.x * C.z;  a1  += q1.x * C.w;  a2  += q0.x * B.x;          \
    a3  += q2.x * B.x;  a4  += q1.x * B.y;  a5  += q0.x * B.z;          \
    a6  += q2.x * B.z;  a7  += q1.x * B.w;  a8  += q0.x * A.x;          \
    a9  += q2.x * A.x;  a10 += q1.x * A.y;  a11 += q0.x * A.z;          \
    a0  += q2.y * C.y;  a1  += q1.y * C.z;  a2  += q0.y * C.w;          \
    a3  += q2.y * C.w;  a4  += q1.y * B.x;  a5  += q0.y * B.y;          \
    a6  += q2.y * B.y;  a7  += q1.y * B.z;  a8  += q0.y * B.w;          \
    a9  += q2.y * B.w;  a10 += q1.y * A.x;  a11 += q0.y * A.y;          \
    a0  += q2.z * C.x;  a1  += q1.z * C.y;  a2  += q0.z * C.z;          \
    a3  += q2.z * C.z;  a4  += q1.z * C.w;  a5  += q0.z * B.x;          \
    a6  += q2.z * B.x;  a7  += q1.z * B.y;  a8  += q0.z * B.z;          \
    a9  += q2.z * B.z;  a10 += q1.z * B.w;  a11 += q0.z * A.x;          \
    a0  += q2.w * D.w;  a1  += q1.w * C.x;  a2  += q0.w * C.y;          \
    a3  += q2.w * C.y;  a4  += q1.w * C.z;  a5  += q0.w * C.w;          \
    a6  += q2.w * C.w;  a7  += q1.w * B.x;  a8  += q0.w * B.y;          \
    a9  += q2.w * B.y;  a10 += q1.w * B.z;  a11 += q0.w * B.w; }

#define GRP12T(g, A, B, C) {                                            \
    const float4 q2 = c2q[g];                                           \
    const float4 q1 = c1q[g];                                           \
    const float4 q0 = c0q[g];                                           \
    a0  += q2.x * C.z;  a1  += q1.x * C.w;  a2  += q0.x * B.x;          \
    a3  += q2.x * B.x;  a4  += q1.x * B.y;  a5  += q0.x * B.z;          \
    a6  += q2.x * B.z;  a7  += q1.x * B.w;  a8  += q0.x * A.x;          \
    a9  += q2.x * A.x;  a10 += q1.x * A.y;  a11 += q0.x * A.z;          \
    a0  += q2.y * C.y;  a1  += q1.y * C.z;  a2  += q0.y * C.w;          \
    a3  += q2.y * C.w;  a4  += q1.y * B.x;  a5  += q0.y * B.y;          \
    a6  += q2.y * B.y;  a7  += q1.y * B.z;  a8  += q0.y * B.w;          \
    a9  += q2.y * B.w;  a10 += q1.y * A.x;  a11 += q0.y * A.y;          \
    a0  += q2.z * C.x;  a1  += q1.z * C.y;  a2  += q0.z * C.z;          \
    a3  += q2.z * C.z;  a4  += q1.z * C.w;  a5  += q0.z * B.x;          \
    a6  += q2.z * B.x;  a7  += q1.z * B.y;  a8  += q0.z * B.z;          \
    a9  += q2.z * B.z;  a10 += q1.z * B.w;  a11 += q0.z * A.x; }

#define CONV12R(P) {                                                    \
    GRP12( 0, P##15, P##14, P##13, P##12);                              \
    GRP12( 1, P##14, P##13, P##12, P##11);                              \
    GRP12( 2, P##13, P##12, P##11, P##10);                              \
    GRP12( 3, P##12, P##11, P##10, P##9);                               \
    GRP12( 4, P##11, P##10, P##9,  P##8);                               \
    GRP12( 5, P##10, P##9,  P##8,  P##7);                               \
    GRP12( 6, P##9,  P##8,  P##7,  P##6);                               \
    GRP12( 7, P##8,  P##7,  P##6,  P##5);                               \
    GRP12( 8, P##7,  P##6,  P##5,  P##4);                               \
    GRP12( 9, P##6,  P##5,  P##4,  P##3);                               \
    GRP12(10, P##5,  P##4,  P##3,  P##2);                               \
    GRP12(11, P##4,  P##3,  P##2,  P##1);                               \
    GRP12(12, P##3,  P##2,  P##1,  P##0);                               \
    GRP12T(13, P##2, P##1, P##0); }

__global__ __launch_bounds__(TPB) void fused_fast(
    const float* __restrict__ x, const float* __restrict__ cp,
    float* __restrict__ out, int n_in, int n_out)
{
    __shared__ alignas(16) float xs0[XT];
    __shared__ alignas(16) float xs1[XT];

    const int tid = threadIdx.x;
    const int t0  = blockIdx.x * TPBK;

    const float4* c2q = (const float4*)(cp + 2 * CPSTRIDE);  // phase 2 (o%3==0)
    const float4* c1q = (const float4*)(cp + 1 * CPSTRIDE);
    const float4* c0q = (const float4*)(cp + 0 * CPSTRIDE);

    // Prologue: stage tile t0 into xs0.
    {
        const int base = 2048 * t0 - 44;
        if (base >= 0 && base + 2104 <= n_in) {
            stage_dma(x, xs0, base, tid);
            if (tid < 56) xs0[2048 + tid] = x[base + 2048 + tid];
        } else {
            stage_edge(x, xs0, base, n_in, tid);
        }
    }
    __syncthreads();

    for (int k = 0; k < TPBK; ++k) {
        const int tile = t0 + k;
        float* cur = (k & 1) ? xs1 : xs0;
        float* nxt = (k & 1) ? xs0 : xs1;

        // A) async prefetch of next tile's main 2048 floats (no wait).
        const int nbase = 2048 * (tile + 1) - 44;
        const bool havenext = (k + 1 < TPBK);
        const bool nxt_int  = (nbase >= 0) && (nbase + 2104 <= n_in);
        if (havenext) {
            if (nxt_int) stage_dma(x, nxt, nbase, tid);
            else         stage_edge(x, nxt, nbase, n_in, tid);  // rare (block 1023)
        }
        __builtin_amdgcn_sched_barrier(0);

        // B) window from current buffer: 16 ds_read_b128, then pure FMA.
        const float4* s4 = (const float4*)cur + 2 * tid;
        const float4 W15 = s4[15], W14 = s4[14], W13 = s4[13], W12 = s4[12];
        const float4 W11 = s4[11], W10 = s4[10], W9  = s4[9],  W8  = s4[8];
        const float4 W7  = s4[7],  W6  = s4[6],  W5  = s4[5],  W4  = s4[4];
        const float4 W3  = s4[3],  W2  = s4[2],  W1  = s4[1],  W0  = s4[0];
        __builtin_amdgcn_sched_barrier(0);

        float a0 = 0.f, a1 = 0.f, a2 = 0.f, a3  = 0.f, a4  = 0.f, a5  = 0.f;
        float a6 = 0.f, a7 = 0.f, a8 = 0.f, a9  = 0.f, a10 = 0.f, a11 = 0.f;
        CONV12R(W);
        __builtin_amdgcn_sched_barrier(0);

        // C) remainder 56 floats of next tile (global load had full FMA shadow).
        if (havenext && nxt_int) {
            if (tid < 56) nxt[2048 + tid] = x[nbase + 2048 + tid];
        }

        // D) store 12 outputs.
        const int ob = tile * OTILE + RPT * tid;
        if (ob >= 50 && ob + 11 < n_out) {
            float4* o4 = (float4*)(out + ob);
            o4[0] = make_float4(a0, a1, a2,  a3);
            o4[1] = make_float4(a4, a5, a6,  a7);
            o4[2] = make_float4(a8, a9, a10, a11);
        } else {
            const float accs[RPT] = {a0,a1,a2,a3,a4,a5,a6,a7,a8,a9,a10,a11};
            for (int d = 0; d < RPT; ++d) {
                const int o = ob + d;
                if (o >= 50 && o < n_out) out[o] = accs[d];
            }
        }
        __syncthreads();   // drains DMA (vmcnt) + LDS ops; swap buffers
    }
}

extern "C" void kernel_launch(void* const* d_in, const int* in_sizes, int n_in_arrs,
                              void* d_out, int out_size, void* d_ws, size_t ws_size,
                              hipStream_t stream) {
    const float* x = (const float*)d_in[0];
    const float* h = (const float*)d_in[1];
    const float* b = (const float*)d_in[2];
    float* out = (float*)d_out;
    float* cp  = (float*)d_ws;                        // 3*56*4 = 672 bytes

    const int n_in  = in_sizes[0];                    // 8388608
    const int n_out = (int)((long long)n_in * 3 / 2); // 12582912 = NTILES*OTILE

    build_coeffs<<<1, 64, 0, stream>>>(h, b, cp);
    fused_fast<<<NBLOCKS, TPB, 0, stream>>>(x, cp, out, n_in, n_out);
    boundary_fix<<<2, 128, 0, stream>>>(x, h, b, out, n_in, n_out, out_size);
}